// Round 1
// baseline (303.992 us; speedup 1.0000x reference)
//
#include <hip/hip_runtime.h>
#include <math.h>

#define BSZ 32
#define SEQ 4096
#define ENCD 512
#define TMAX 64

__device__ __forceinline__ float dot4(float4 a, float4 b) {
    return a.x * b.x + a.y * b.y + a.z * b.z + a.w * b.w;
}

// Stage 1: one 64-lane block per (b,t). Gathers the encoder row, computes
// left[b,t,0..1] and right[b,t,0..1] via wave-reduced dot products.
__global__ __launch_bounds__(64) void lr_kernel(
    const float* __restrict__ enc, const int* __restrict__ ids,
    const float* __restrict__ W, float4* __restrict__ lr) {
    int bt = blockIdx.x;              // b*64 + t
    int b = bt >> 6;
    int lane = threadIdx.x;           // 0..63, 8 floats each
    int id = ids[bt];
    const float4* x4 = (const float4*)(enc + ((size_t)b * SEQ + (size_t)id) * ENCD) + lane * 2;
    // W is (2, 2*ENC) row-major: Wl0=W[0][:512], Wr0=W[0][512:], Wl1=W[1][:512], Wr1=W[1][512:]
    const float4* wl0 = (const float4*)(W) + lane * 2;
    const float4* wr0 = (const float4*)(W + ENCD) + lane * 2;
    const float4* wl1 = (const float4*)(W + 2 * ENCD) + lane * 2;
    const float4* wr1 = (const float4*)(W + 3 * ENCD) + lane * 2;

    float4 xa = x4[0], xb = x4[1];
    float s0 = dot4(xa, wl0[0]) + dot4(xb, wl0[1]);   // left, o=0
    float s1 = dot4(xa, wl1[0]) + dot4(xb, wl1[1]);   // left, o=1
    float s2 = dot4(xa, wr0[0]) + dot4(xb, wr0[1]);   // right, o=0
    float s3 = dot4(xa, wr1[0]) + dot4(xb, wr1[1]);   // right, o=1

#pragma unroll
    for (int off = 32; off; off >>= 1) {
        s0 += __shfl_down(s0, off);
        s1 += __shfl_down(s1, off);
        s2 += __shfl_down(s2, off);
        s3 += __shfl_down(s3, off);
    }
    if (lane == 0) lr[bt] = make_float4(s0, s1, s2, s3);
}

// Stage 2: one block per batch; iterate all (j,k) pairs, masked CE accumulate.
__global__ __launch_bounds__(256) void pair_kernel(
    const float4* __restrict__ lr, const int* __restrict__ tlen,
    const float* __restrict__ bias, float* __restrict__ partial) {
    int b = blockIdx.x;
    int tid = threadIdx.x;
    __shared__ float4 slr[TMAX];
    __shared__ float ssum[4], scnt[4];
    if (tid < TMAX) slr[tid] = lr[b * TMAX + tid];
    __syncthreads();

    int T = tlen[b];
    float b0 = bias[0], b1 = bias[1];
    float sum = 0.f, cnt = 0.f;
    for (int idx = tid; idx < TMAX * TMAX; idx += 256) {
        int j = idx >> 6, k = idx & 63;
        if (k < j && j < T) {
            float4 Lj = slr[j];
            float4 Rk = slr[k];
            float l0 = Lj.x + Rk.z + b0;
            float l1 = Lj.y + Rk.w + b1;
            float m = fmaxf(l0, l1);
            float lse = m + logf(expf(l0 - m) + expf(l1 - m));
            float lp = (k == j - 1) ? (l1 - lse) : (l0 - lse);
            sum -= lp;
            cnt += 1.f;
        }
    }
#pragma unroll
    for (int off = 32; off; off >>= 1) {
        sum += __shfl_down(sum, off);
        cnt += __shfl_down(cnt, off);
    }
    int wave = tid >> 6;
    if ((tid & 63) == 0) { ssum[wave] = sum; scnt[wave] = cnt; }
    __syncthreads();
    if (tid == 0) {
        float S = ssum[0] + ssum[1] + ssum[2] + ssum[3];
        float C = scnt[0] + scnt[1] + scnt[2] + scnt[3];
        partial[b * 2] = S;
        partial[b * 2 + 1] = C;
    }
}

// Stage 3: reduce 32 per-batch partials -> scalar loss.
__global__ __launch_bounds__(64) void final_kernel(
    const float* __restrict__ partial, float* __restrict__ out) {
    int lane = threadIdx.x;
    float s = 0.f, c = 0.f;
    if (lane < BSZ) { s = partial[lane * 2]; c = partial[lane * 2 + 1]; }
#pragma unroll
    for (int off = 32; off; off >>= 1) {
        s += __shfl_down(s, off);
        c += __shfl_down(c, off);
    }
    if (lane == 0) out[0] = s / fmaxf(c, 1.f);
}

extern "C" void kernel_launch(void* const* d_in, const int* in_sizes, int n_in,
                              void* d_out, int out_size, void* d_ws, size_t ws_size,
                              hipStream_t stream) {
    const float* enc  = (const float*)d_in[0];   // (32, 4096, 512) f32
    const int*   ids  = (const int*)d_in[1];     // (32, 64) i32
    const int*   tlen = (const int*)d_in[2];     // (32,) i32
    const float* W    = (const float*)d_in[3];   // (2, 1024) f32
    const float* bias = (const float*)d_in[4];   // (2,) f32
    float* out = (float*)d_out;

    float4* lr      = (float4*)d_ws;                       // 2048 float4 = 32 KB
    float*  partial = (float*)((char*)d_ws + BSZ * TMAX * sizeof(float4)); // 64 floats

    lr_kernel<<<BSZ * TMAX, 64, 0, stream>>>(enc, ids, W, lr);
    pair_kernel<<<BSZ, 256, 0, stream>>>(lr, tlen, bias, partial);
    final_kernel<<<1, 64, 0, stream>>>(partial, out);
}